// Round 1
// baseline (71653.497 us; speedup 1.0000x reference)
//
#include <hip/hip_runtime.h>
#include <stdint.h>

#define B_ 8
#define S_ 4096
#define DIN 2048
#define DH 512
#define NG3 1536   // 3 gates * DH
#define NG 16      // workgroups per batch element in the scan
#define ROWS 32    // hidden rows owned per scan workgroup (DH/NG)

typedef __attribute__((ext_vector_type(8))) short bf16x8;
typedef __attribute__((ext_vector_type(4))) float f32x4;

__device__ __forceinline__ unsigned short f2bf(float f) {
  unsigned int u = __builtin_bit_cast(unsigned int, f);
  u = u + 0x7FFFu + ((u >> 16) & 1u);   // RNE
  return (unsigned short)(u >> 16);
}
__device__ __forceinline__ float bf2f(unsigned short h) {
  unsigned int u = ((unsigned int)h) << 16;
  return __builtin_bit_cast(float, u);
}

// ---------------------------------------------------------------------------
// init: zero the GRU state + sync counters (ws is poisoned 0xAA every call)
// ---------------------------------------------------------------------------
__global__ void init_state(float* H, float* V, int* cnt) {
  int tid = threadIdx.x;
  for (int i = tid; i < B_ * DH; i += 256) { H[i] = 0.f; V[i] = 0.f; }
  if (tid < 16) cnt[tid] = 0;
}

// ---------------------------------------------------------------------------
// pack x-side gate weights into Wp[1536][512] bf16 (K-major B operand)
// rows 0..511 = W_z[:, :512], 512..1023 = W_r[:, :512], 1024..1535 = W_h[:, :512]
// ---------------------------------------------------------------------------
__global__ void pack_w(const float* __restrict__ Wz, const float* __restrict__ Wr,
                       const float* __restrict__ Wh, unsigned short* __restrict__ Wp) {
  int id = blockIdx.x * blockDim.x + threadIdx.x;
  if (id >= NG3 * DH) return;
  int n = id >> 9, k = id & 511;
  float v;
  if (n < 512)       v = Wz[(size_t)n * 1024 + k];
  else if (n < 1024) v = Wr[(size_t)(n - 512) * 1024 + k];
  else               v = Wh[(size_t)(n - 1024) * 1024 + k];
  Wp[id] = f2bf(v);
}

// ---------------------------------------------------------------------------
// GEMM1: seq[32768][512] (bf16) = X[32768][2048] (f32, converted on the fly)
//        @ Wlm[512][2048]^T. 64x64 tile, BK=32, 4 waves, MFMA 16x16x32 bf16.
// ---------------------------------------------------------------------------
__global__ __launch_bounds__(256) void gemm1_kernel(
    const float* __restrict__ X, const float* __restrict__ Wlm,
    unsigned short* __restrict__ seqb) {
  __shared__ __align__(16) unsigned short sA[64 * 32];
  __shared__ __align__(16) unsigned short sB[64 * 32];
  const int tid = threadIdx.x;
  const int m0 = blockIdx.x * 64, n0 = blockIdx.y * 64;
  const int lrow = tid >> 2, lpart = tid & 3;
  const int w = tid >> 6, lane = tid & 63;
  const int wm = (w >> 1) * 32, wn = (w & 1) * 32;
  const int l16 = lane & 15, quad = lane >> 4;
  f32x4 acc00 = {0.f, 0.f, 0.f, 0.f}, acc01 = {0.f, 0.f, 0.f, 0.f};
  f32x4 acc10 = {0.f, 0.f, 0.f, 0.f}, acc11 = {0.f, 0.f, 0.f, 0.f};
  const float* ap = X + (size_t)(m0 + lrow) * DIN + lpart * 8;
  const float* bp = Wlm + (size_t)(n0 + lrow) * DIN + lpart * 8;
  for (int k0 = 0; k0 < DIN; k0 += 32) {
    float4 a1 = *(const float4*)(ap + k0);
    float4 a2 = *(const float4*)(ap + k0 + 4);
    float4 b1 = *(const float4*)(bp + k0);
    float4 b2 = *(const float4*)(bp + k0 + 4);
    uint4 pa, pb;
    pa.x = f2bf(a1.x) | ((unsigned)f2bf(a1.y) << 16);
    pa.y = f2bf(a1.z) | ((unsigned)f2bf(a1.w) << 16);
    pa.z = f2bf(a2.x) | ((unsigned)f2bf(a2.y) << 16);
    pa.w = f2bf(a2.z) | ((unsigned)f2bf(a2.w) << 16);
    pb.x = f2bf(b1.x) | ((unsigned)f2bf(b1.y) << 16);
    pb.y = f2bf(b1.z) | ((unsigned)f2bf(b1.w) << 16);
    pb.z = f2bf(b2.x) | ((unsigned)f2bf(b2.y) << 16);
    pb.w = f2bf(b2.z) | ((unsigned)f2bf(b2.w) << 16);
    __syncthreads();
    *(uint4*)(sA + lrow * 32 + lpart * 8) = pa;
    *(uint4*)(sB + lrow * 32 + lpart * 8) = pb;
    __syncthreads();
    uint4 ua0 = *(const uint4*)(sA + (wm + l16) * 32 + quad * 8);
    uint4 ua1 = *(const uint4*)(sA + (wm + 16 + l16) * 32 + quad * 8);
    uint4 ub0 = *(const uint4*)(sB + (wn + l16) * 32 + quad * 8);
    uint4 ub1 = *(const uint4*)(sB + (wn + 16 + l16) * 32 + quad * 8);
    bf16x8 a0 = __builtin_bit_cast(bf16x8, ua0);
    bf16x8 a1f = __builtin_bit_cast(bf16x8, ua1);
    bf16x8 b0 = __builtin_bit_cast(bf16x8, ub0);
    bf16x8 b1f = __builtin_bit_cast(bf16x8, ub1);
    acc00 = __builtin_amdgcn_mfma_f32_16x16x32_bf16(a0, b0, acc00, 0, 0, 0);
    acc01 = __builtin_amdgcn_mfma_f32_16x16x32_bf16(a0, b1f, acc01, 0, 0, 0);
    acc10 = __builtin_amdgcn_mfma_f32_16x16x32_bf16(a1f, b0, acc10, 0, 0, 0);
    acc11 = __builtin_amdgcn_mfma_f32_16x16x32_bf16(a1f, b1f, acc11, 0, 0, 0);
  }
#pragma unroll
  for (int r = 0; r < 4; ++r) {
    int row0 = m0 + wm + quad * 4 + r;
    int row1 = row0 + 16;
    int col0 = n0 + wn + l16;
    seqb[(size_t)row0 * DH + col0] = f2bf(acc00[r]);
    seqb[(size_t)row0 * DH + col0 + 16] = f2bf(acc01[r]);
    seqb[(size_t)row1 * DH + col0] = f2bf(acc10[r]);
    seqb[(size_t)row1 * DH + col0 + 16] = f2bf(acc11[r]);
  }
}

// ---------------------------------------------------------------------------
// GEMM2: G[32768][1536] (bf16) = seq[32768][512] (bf16) @ Wp[1536][512]^T
// ---------------------------------------------------------------------------
__global__ __launch_bounds__(256) void gemm2_kernel(
    const unsigned short* __restrict__ Ab, const unsigned short* __restrict__ Bb,
    unsigned short* __restrict__ Cb) {
  __shared__ __align__(16) unsigned short sA[64 * 32];
  __shared__ __align__(16) unsigned short sB[64 * 32];
  const int tid = threadIdx.x;
  const int m0 = blockIdx.x * 64, n0 = blockIdx.y * 64;
  const int lrow = tid >> 2, lpart = tid & 3;
  const int w = tid >> 6, lane = tid & 63;
  const int wm = (w >> 1) * 32, wn = (w & 1) * 32;
  const int l16 = lane & 15, quad = lane >> 4;
  f32x4 acc00 = {0.f, 0.f, 0.f, 0.f}, acc01 = {0.f, 0.f, 0.f, 0.f};
  f32x4 acc10 = {0.f, 0.f, 0.f, 0.f}, acc11 = {0.f, 0.f, 0.f, 0.f};
  const unsigned short* ap = Ab + (size_t)(m0 + lrow) * DH + lpart * 8;
  const unsigned short* bp = Bb + (size_t)(n0 + lrow) * DH + lpart * 8;
  for (int k0 = 0; k0 < DH; k0 += 32) {
    uint4 pa = *(const uint4*)(ap + k0);
    uint4 pb = *(const uint4*)(bp + k0);
    __syncthreads();
    *(uint4*)(sA + lrow * 32 + lpart * 8) = pa;
    *(uint4*)(sB + lrow * 32 + lpart * 8) = pb;
    __syncthreads();
    uint4 ua0 = *(const uint4*)(sA + (wm + l16) * 32 + quad * 8);
    uint4 ua1 = *(const uint4*)(sA + (wm + 16 + l16) * 32 + quad * 8);
    uint4 ub0 = *(const uint4*)(sB + (wn + l16) * 32 + quad * 8);
    uint4 ub1 = *(const uint4*)(sB + (wn + 16 + l16) * 32 + quad * 8);
    bf16x8 a0 = __builtin_bit_cast(bf16x8, ua0);
    bf16x8 a1f = __builtin_bit_cast(bf16x8, ua1);
    bf16x8 b0 = __builtin_bit_cast(bf16x8, ub0);
    bf16x8 b1f = __builtin_bit_cast(bf16x8, ub1);
    acc00 = __builtin_amdgcn_mfma_f32_16x16x32_bf16(a0, b0, acc00, 0, 0, 0);
    acc01 = __builtin_amdgcn_mfma_f32_16x16x32_bf16(a0, b1f, acc01, 0, 0, 0);
    acc10 = __builtin_amdgcn_mfma_f32_16x16x32_bf16(a1f, b0, acc10, 0, 0, 0);
    acc11 = __builtin_amdgcn_mfma_f32_16x16x32_bf16(a1f, b1f, acc11, 0, 0, 0);
  }
#pragma unroll
  for (int r = 0; r < 4; ++r) {
    int row0 = m0 + wm + quad * 4 + r;
    int row1 = row0 + 16;
    int col0 = n0 + wn + l16;
    Cb[(size_t)row0 * NG3 + col0] = f2bf(acc00[r]);
    Cb[(size_t)row0 * NG3 + col0 + 16] = f2bf(acc01[r]);
    Cb[(size_t)row1 * NG3 + col0] = f2bf(acc10[r]);
    Cb[(size_t)row1 * NG3 + col0 + 16] = f2bf(acc11[r]);
  }
}

// ---------------------------------------------------------------------------
// GRU scan. Grid = 128 WGs (16 per batch element). WG (b, slice) owns hidden
// rows [slice*32, slice*32+32); recurrent weight slices live in REGISTERS
// (fp32, exact). Two agent-scope sync phases per step via monotonic counters.
// Cross-WG data (H, V) uses agent-scope atomics (per-XCD L2 non-coherent).
// Launched cooperatively so all 128 blocks are co-resident (spin-wait safe).
// ---------------------------------------------------------------------------
__global__ __launch_bounds__(256, 1) void scan_kernel(
    const unsigned short* __restrict__ G, const float* __restrict__ Wz,
    const float* __restrict__ Wr, const float* __restrict__ Wh,
    float* __restrict__ H, float* __restrict__ V,
    int* __restrict__ cntA, int* __restrict__ cntB) {
  const int tid = threadIdx.x;
  const int wg = blockIdx.x;
  const int b = wg & 7;          // batch: wg%8 -> XCD-affine grouping heuristic
  const int slice = wg >> 3;
  const int rbase = slice * ROWS;

  // phase A mapping: (gate z/r, row, 4 lanes x 128 cols)
  const int rgA = tid >> 2, gateA = rgA >> 5, rowA = rgA & 31, part4 = tid & 3;
  // phase B mapping: (row, 8 lanes x 64 cols)
  const int rowB = tid >> 3, part8 = tid & 7;

  const float* WAp = ((gateA == 0) ? Wz : Wr) + (size_t)(rbase + rowA) * 1024 + 512 + part4 * 128;
  const float* WBp = Wh + (size_t)(rbase + rowB) * 1024 + 512 + part8 * 64;
  float wA[128];
#pragma unroll
  for (int c = 0; c < 128; c += 4) {
    float4 t = *(const float4*)(WAp + c);
    wA[c] = t.x; wA[c + 1] = t.y; wA[c + 2] = t.z; wA[c + 3] = t.w;
  }
  float wB[64];
#pragma unroll
  for (int c = 0; c < 64; c += 4) {
    float4 t = *(const float4*)(WBp + c);
    wB[c] = t.x; wB[c + 1] = t.y; wB[c + 2] = t.z; wB[c + 3] = t.w;
  }

  __shared__ float hbuf[DH];
  __shared__ float vbuf[DH];
  __shared__ float gz[ROWS], gr[ROWS], gh[ROWS], zb[ROWS];

  int* cA = cntA + b;
  int* cB = cntB + b;
  float* Hb = H + b * DH;
  float* Vb = V + b * DH;
  const unsigned short* Gb = G + (size_t)b * S_ * NG3;

  for (int t = 0; t < S_; ++t) {
    // prefetch this step's gate biases (overlaps the poll)
    float gval = 0.f;
    if (tid < 96) {
      int gate = tid >> 5, i = tid & 31;
      gval = bf2f(Gb[(size_t)t * NG3 + gate * 512 + rbase + i]);
    }
    // wait for h^(t) from all WGs of this batch group
    if (t > 0 && tid == 0) {
      const int target = NG * t;
      while (__hip_atomic_load(cB, __ATOMIC_RELAXED, __HIP_MEMORY_SCOPE_AGENT) < target) {}
      __threadfence();
    }
    __syncthreads();
    float h0 = __hip_atomic_load(Hb + 2 * tid, __ATOMIC_RELAXED, __HIP_MEMORY_SCOPE_AGENT);
    float h1 = __hip_atomic_load(Hb + 2 * tid + 1, __ATOMIC_RELAXED, __HIP_MEMORY_SCOPE_AGENT);
    hbuf[2 * tid] = h0;
    hbuf[2 * tid + 1] = h1;
    if (tid < 32) gz[tid] = gval;
    else if (tid < 64) gr[tid - 32] = gval;
    else if (tid < 96) gh[tid - 64] = gval;
    __syncthreads();

    // ---- phase A: z and r rows; publish v = r (.) h for our slice ----
    {
      const float* hc = hbuf + part4 * 128;
      float s = 0.f;
#pragma unroll
      for (int c = 0; c < 128; c += 4) {
        float4 hv = *(const float4*)(hc + c);
        s += wA[c] * hv.x + wA[c + 1] * hv.y + wA[c + 2] * hv.z + wA[c + 3] * hv.w;
      }
      s += __shfl_xor(s, 1);
      s += __shfl_xor(s, 2);
      if (part4 == 0) {
        float a = (gateA ? gr[rowA] : gz[rowA]) + s;
        float act = 1.f / (1.f + expf(-a));
        if (gateA == 0) {
          zb[rowA] = act;
        } else {
          float v = act * hbuf[rbase + rowA];
          __hip_atomic_store(Vb + rbase + rowA, v, __ATOMIC_RELAXED, __HIP_MEMORY_SCOPE_AGENT);
        }
      }
    }
    __syncthreads();
    if (tid == 0) {
      __threadfence();
      __hip_atomic_fetch_add(cA, 1, __ATOMIC_RELEASE, __HIP_MEMORY_SCOPE_AGENT);
      const int target = NG * (t + 1);
      while (__hip_atomic_load(cA, __ATOMIC_RELAXED, __HIP_MEMORY_SCOPE_AGENT) < target) {}
      __threadfence();
    }
    __syncthreads();
    {
      float v0 = __hip_atomic_load(Vb + 2 * tid, __ATOMIC_RELAXED, __HIP_MEMORY_SCOPE_AGENT);
      float v1 = __hip_atomic_load(Vb + 2 * tid + 1, __ATOMIC_RELAXED, __HIP_MEMORY_SCOPE_AGENT);
      vbuf[2 * tid] = v0;
      vbuf[2 * tid + 1] = v1;
    }
    __syncthreads();

    // ---- phase B: h' rows, combine, publish h_new for our slice ----
    {
      const float* vc = vbuf + part8 * 64;
      float s2 = 0.f;
#pragma unroll
      for (int c = 0; c < 64; c += 4) {
        float4 vv = *(const float4*)(vc + c);
        s2 += wB[c] * vv.x + wB[c + 1] * vv.y + wB[c + 2] * vv.z + wB[c + 3] * vv.w;
      }
      s2 += __shfl_xor(s2, 1);
      s2 += __shfl_xor(s2, 2);
      s2 += __shfl_xor(s2, 4);
      if (part8 == 0) {
        float hp = tanhf(gh[rowB] + s2);
        float z = zb[rowB];
        float hold = hbuf[rbase + rowB];
        float hn = (1.f - z) * hold + z * hp;
        __hip_atomic_store(Hb + rbase + rowB, hn, __ATOMIC_RELAXED, __HIP_MEMORY_SCOPE_AGENT);
      }
    }
    __syncthreads();   // protects hbuf/vbuf/g*/zb reuse next iteration
    if (tid == 0) {
      __threadfence();
      __hip_atomic_fetch_add(cB, 1, __ATOMIC_RELEASE, __HIP_MEMORY_SCOPE_AGENT);
    }
  }
}

// ---------------------------------------------------------------------------
// classifier: out[8][10] = h_final @ W_c^T
// ---------------------------------------------------------------------------
__global__ void classifier_kernel(const float* __restrict__ H,
                                  const float* __restrict__ Wc,
                                  float* __restrict__ out) {
  int tid = threadIdx.x;
  if (tid < 80) {
    int b = tid / 10, c = tid % 10;
    const float* h = H + b * DH;
    const float* w = Wc + (size_t)c * DH;
    float s = 0.f;
    for (int i = 0; i < DH; i += 4) {
      float4 hv = *(const float4*)(h + i);
      float4 wv = *(const float4*)(w + i);
      s += hv.x * wv.x + hv.y * wv.y + hv.z * wv.z + hv.w * wv.w;
    }
    out[tid] = s;
  }
}

extern "C" void kernel_launch(void* const* d_in, const int* in_sizes, int n_in,
                              void* d_out, int out_size, void* d_ws, size_t ws_size,
                              hipStream_t stream) {
  const float* X = (const float*)d_in[0];
  const float* Wlm = (const float*)d_in[1];
  const float* Wz = (const float*)d_in[2];
  const float* Wr = (const float*)d_in[3];
  const float* Wh = (const float*)d_in[4];
  const float* Wc = (const float*)d_in[5];
  float* out = (float*)d_out;

  char* ws = (char*)d_ws;
  unsigned short* seqb = (unsigned short*)ws;              // 33,554,432 B
  unsigned short* G = (unsigned short*)(ws + 33554432);    // 100,663,296 B
  unsigned short* Wp = (unsigned short*)(ws + 134217728);  // 1,572,864 B
  float* H = (float*)(ws + 135790592);                     // 16 KB
  float* V = (float*)(ws + 135806976);                     // 16 KB
  int* cnt = (int*)(ws + 135823360);                       // 16 ints (cntA | cntB)

  init_state<<<1, 256, 0, stream>>>(H, V, cnt);
  pack_w<<<768, 1024, 0, stream>>>(Wz, Wr, Wh, Wp);
  gemm1_kernel<<<dim3(512, 8), 256, 0, stream>>>(X, Wlm, seqb);
  gemm2_kernel<<<dim3(512, 24), 256, 0, stream>>>(seqb, Wp, G);

  {
    const unsigned short* Gc = G;
    int* cA = cnt;
    int* cB = cnt + 8;
    void* args[] = {(void*)&Gc, (void*)&Wz, (void*)&Wr, (void*)&Wh,
                    (void*)&H, (void*)&V, (void*)&cA, (void*)&cB};
    hipLaunchCooperativeKernel((const void*)scan_kernel, dim3(NG * B_), dim3(256),
                               args, 0, stream);
  }
  classifier_kernel<<<1, 128, 0, stream>>>(H, Wc, out);
}

// Round 2
// 21364.662 us; speedup vs baseline: 3.3538x; 3.3538x over previous
//
#include <hip/hip_runtime.h>
#include <stdint.h>

#define B_ 8
#define S_ 4096
#define DIN 2048
#define DH 512
#define NG3 1536   // 3 gates * DH
#define NG 16      // workgroups per batch element in the scan
#define ROWS 32    // hidden rows owned per scan workgroup (DH/NG)
#define WSTRIDE 260  // padded LDS row stride in uints (256 + 4 -> breaks bank aliasing)

typedef __attribute__((ext_vector_type(8))) short bf16x8;
typedef __attribute__((ext_vector_type(4))) float f32x4;

__device__ __forceinline__ unsigned short f2bf(float f) {
  unsigned int u = __builtin_bit_cast(unsigned int, f);
  u = u + 0x7FFFu + ((u >> 16) & 1u);   // RNE
  return (unsigned short)(u >> 16);
}
__device__ __forceinline__ float bf2f(unsigned short h) {
  unsigned int u = ((unsigned int)h) << 16;
  return __builtin_bit_cast(float, u);
}
__device__ __forceinline__ float bflo(unsigned u) {
  return __builtin_bit_cast(float, u << 16);
}
__device__ __forceinline__ float bfhi(unsigned u) {
  return __builtin_bit_cast(float, u & 0xFFFF0000u);
}
__device__ __forceinline__ unsigned long long tagword(unsigned tag, float v) {
  return ((unsigned long long)tag << 32) | (unsigned long long)__builtin_bit_cast(unsigned, v);
}

// ---------------------------------------------------------------------------
// init: zero the tagged exchange arrays (tag 0 == initial state h=0, v invalid)
// ---------------------------------------------------------------------------
__global__ void init_state(unsigned long long* H8, unsigned long long* V8) {
  int tid = threadIdx.x;
  for (int i = tid; i < B_ * DH; i += 256) { H8[i] = 0ULL; V8[i] = 0ULL; }
}

// ---------------------------------------------------------------------------
// pack x-side gate weights into Wp[1536][512] bf16 (K-major B operand)
// ---------------------------------------------------------------------------
__global__ void pack_w(const float* __restrict__ Wz, const float* __restrict__ Wr,
                       const float* __restrict__ Wh, unsigned short* __restrict__ Wp) {
  int id = blockIdx.x * blockDim.x + threadIdx.x;
  if (id >= NG3 * DH) return;
  int n = id >> 9, k = id & 511;
  float v;
  if (n < 512)       v = Wz[(size_t)n * 1024 + k];
  else if (n < 1024) v = Wr[(size_t)(n - 512) * 1024 + k];
  else               v = Wh[(size_t)(n - 1024) * 1024 + k];
  Wp[id] = f2bf(v);
}

// ---------------------------------------------------------------------------
// GEMM1: seq[32768][512] (bf16) = X[32768][2048] (f32->bf16) @ Wlm[512][2048]^T
// ---------------------------------------------------------------------------
__global__ __launch_bounds__(256) void gemm1_kernel(
    const float* __restrict__ X, const float* __restrict__ Wlm,
    unsigned short* __restrict__ seqb) {
  __shared__ __align__(16) unsigned short sA[64 * 32];
  __shared__ __align__(16) unsigned short sB[64 * 32];
  const int tid = threadIdx.x;
  const int m0 = blockIdx.x * 64, n0 = blockIdx.y * 64;
  const int lrow = tid >> 2, lpart = tid & 3;
  const int w = tid >> 6, lane = tid & 63;
  const int wm = (w >> 1) * 32, wn = (w & 1) * 32;
  const int l16 = lane & 15, quad = lane >> 4;
  f32x4 acc00 = {0.f, 0.f, 0.f, 0.f}, acc01 = {0.f, 0.f, 0.f, 0.f};
  f32x4 acc10 = {0.f, 0.f, 0.f, 0.f}, acc11 = {0.f, 0.f, 0.f, 0.f};
  const float* ap = X + (size_t)(m0 + lrow) * DIN + lpart * 8;
  const float* bp = Wlm + (size_t)(n0 + lrow) * DIN + lpart * 8;
  for (int k0 = 0; k0 < DIN; k0 += 32) {
    float4 a1 = *(const float4*)(ap + k0);
    float4 a2 = *(const float4*)(ap + k0 + 4);
    float4 b1 = *(const float4*)(bp + k0);
    float4 b2 = *(const float4*)(bp + k0 + 4);
    uint4 pa, pb;
    pa.x = f2bf(a1.x) | ((unsigned)f2bf(a1.y) << 16);
    pa.y = f2bf(a1.z) | ((unsigned)f2bf(a1.w) << 16);
    pa.z = f2bf(a2.x) | ((unsigned)f2bf(a2.y) << 16);
    pa.w = f2bf(a2.z) | ((unsigned)f2bf(a2.w) << 16);
    pb.x = f2bf(b1.x) | ((unsigned)f2bf(b1.y) << 16);
    pb.y = f2bf(b1.z) | ((unsigned)f2bf(b1.w) << 16);
    pb.z = f2bf(b2.x) | ((unsigned)f2bf(b2.y) << 16);
    pb.w = f2bf(b2.z) | ((unsigned)f2bf(b2.w) << 16);
    __syncthreads();
    *(uint4*)(sA + lrow * 32 + lpart * 8) = pa;
    *(uint4*)(sB + lrow * 32 + lpart * 8) = pb;
    __syncthreads();
    uint4 ua0 = *(const uint4*)(sA + (wm + l16) * 32 + quad * 8);
    uint4 ua1 = *(const uint4*)(sA + (wm + 16 + l16) * 32 + quad * 8);
    uint4 ub0 = *(const uint4*)(sB + (wn + l16) * 32 + quad * 8);
    uint4 ub1 = *(const uint4*)(sB + (wn + 16 + l16) * 32 + quad * 8);
    bf16x8 a0 = __builtin_bit_cast(bf16x8, ua0);
    bf16x8 a1f = __builtin_bit_cast(bf16x8, ua1);
    bf16x8 b0 = __builtin_bit_cast(bf16x8, ub0);
    bf16x8 b1f = __builtin_bit_cast(bf16x8, ub1);
    acc00 = __builtin_amdgcn_mfma_f32_16x16x32_bf16(a0, b0, acc00, 0, 0, 0);
    acc01 = __builtin_amdgcn_mfma_f32_16x16x32_bf16(a0, b1f, acc01, 0, 0, 0);
    acc10 = __builtin_amdgcn_mfma_f32_16x16x32_bf16(a1f, b0, acc10, 0, 0, 0);
    acc11 = __builtin_amdgcn_mfma_f32_16x16x32_bf16(a1f, b1f, acc11, 0, 0, 0);
  }
#pragma unroll
  for (int r = 0; r < 4; ++r) {
    int row0 = m0 + wm + quad * 4 + r;
    int row1 = row0 + 16;
    int col0 = n0 + wn + l16;
    seqb[(size_t)row0 * DH + col0] = f2bf(acc00[r]);
    seqb[(size_t)row0 * DH + col0 + 16] = f2bf(acc01[r]);
    seqb[(size_t)row1 * DH + col0] = f2bf(acc10[r]);
    seqb[(size_t)row1 * DH + col0 + 16] = f2bf(acc11[r]);
  }
}

// ---------------------------------------------------------------------------
// GEMM2: G[32768][1536] (bf16) = seq[32768][512] (bf16) @ Wp[1536][512]^T
// ---------------------------------------------------------------------------
__global__ __launch_bounds__(256) void gemm2_kernel(
    const unsigned short* __restrict__ Ab, const unsigned short* __restrict__ Bb,
    unsigned short* __restrict__ Cb) {
  __shared__ __align__(16) unsigned short sA[64 * 32];
  __shared__ __align__(16) unsigned short sB[64 * 32];
  const int tid = threadIdx.x;
  const int m0 = blockIdx.x * 64, n0 = blockIdx.y * 64;
  const int lrow = tid >> 2, lpart = tid & 3;
  const int w = tid >> 6, lane = tid & 63;
  const int wm = (w >> 1) * 32, wn = (w & 1) * 32;
  const int l16 = lane & 15, quad = lane >> 4;
  f32x4 acc00 = {0.f, 0.f, 0.f, 0.f}, acc01 = {0.f, 0.f, 0.f, 0.f};
  f32x4 acc10 = {0.f, 0.f, 0.f, 0.f}, acc11 = {0.f, 0.f, 0.f, 0.f};
  const unsigned short* ap = Ab + (size_t)(m0 + lrow) * DH + lpart * 8;
  const unsigned short* bp = Bb + (size_t)(n0 + lrow) * DH + lpart * 8;
  for (int k0 = 0; k0 < DH; k0 += 32) {
    uint4 pa = *(const uint4*)(ap + k0);
    uint4 pb = *(const uint4*)(bp + k0);
    __syncthreads();
    *(uint4*)(sA + lrow * 32 + lpart * 8) = pa;
    *(uint4*)(sB + lrow * 32 + lpart * 8) = pb;
    __syncthreads();
    uint4 ua0 = *(const uint4*)(sA + (wm + l16) * 32 + quad * 8);
    uint4 ua1 = *(const uint4*)(sA + (wm + 16 + l16) * 32 + quad * 8);
    uint4 ub0 = *(const uint4*)(sB + (wn + l16) * 32 + quad * 8);
    uint4 ub1 = *(const uint4*)(sB + (wn + 16 + l16) * 32 + quad * 8);
    bf16x8 a0 = __builtin_bit_cast(bf16x8, ua0);
    bf16x8 a1f = __builtin_bit_cast(bf16x8, ua1);
    bf16x8 b0 = __builtin_bit_cast(bf16x8, ub0);
    bf16x8 b1f = __builtin_bit_cast(bf16x8, ub1);
    acc00 = __builtin_amdgcn_mfma_f32_16x16x32_bf16(a0, b0, acc00, 0, 0, 0);
    acc01 = __builtin_amdgcn_mfma_f32_16x16x32_bf16(a0, b1f, acc01, 0, 0, 0);
    acc10 = __builtin_amdgcn_mfma_f32_16x16x32_bf16(a1f, b0, acc10, 0, 0, 0);
    acc11 = __builtin_amdgcn_mfma_f32_16x16x32_bf16(a1f, b1f, acc11, 0, 0, 0);
  }
#pragma unroll
  for (int r = 0; r < 4; ++r) {
    int row0 = m0 + wm + quad * 4 + r;
    int row1 = row0 + 16;
    int col0 = n0 + wn + l16;
    Cb[(size_t)row0 * NG3 + col0] = f2bf(acc00[r]);
    Cb[(size_t)row0 * NG3 + col0 + 16] = f2bf(acc01[r]);
    Cb[(size_t)row1 * NG3 + col0] = f2bf(acc10[r]);
    Cb[(size_t)row1 * NG3 + col0 + 16] = f2bf(acc11[r]);
  }
}

// ---------------------------------------------------------------------------
// GRU scan — tagged-word exchange, NO fences, NO counters.
// H8/V8: one ulong per hidden element: hi32 = step tag, lo32 = fp32 value.
// A word with tag T is only overwritten after every reader consumed tag T
// (proof: V-gather(t+1) of every WG precedes any H-publish(t+1); H-gather(t)
// of every WG precedes any V-publish(t+2) — the tag chain forms the barrier).
// Recurrent weights live in LDS as bf16 (staged once).
// ---------------------------------------------------------------------------
__global__ __launch_bounds__(256) void scan_kernel(
    const unsigned short* __restrict__ G, const float* __restrict__ Wz,
    const float* __restrict__ Wr, const float* __restrict__ Wh,
    unsigned long long* __restrict__ H8, unsigned long long* __restrict__ V8) {
  extern __shared__ char smem[];
  unsigned* sWZR = (unsigned*)smem;                 // 2*32 rows * 260 -> 66560 B
  unsigned* sWH  = (unsigned*)(smem + 66560);       // 32 rows  * 260 -> 33280 B
  float* hbuf = (float*)(smem + 99840);             // 512 f
  float* vbuf = (float*)(smem + 101888);            // 512 f
  float* gz   = (float*)(smem + 103936);            // 32 f
  float* gr   = gz + 32;
  float* gh   = gz + 64;
  float* zb   = gz + 96;

  const int tid = threadIdx.x;
  const int wg = blockIdx.x;
  const int b = wg & 7;
  const int slice = wg >> 3;
  const int rbase = slice * ROWS;

  // ---- stage recurrent-weight slices (h-half columns) into LDS as bf16 ----
  for (int idx = tid; idx < 3 * ROWS * 256; idx += 256) {
    int g = idx >> 13;            // / 8192
    int rem = idx & 8191;
    int row = rem >> 8, cu = rem & 255;
    const float* src = (g == 0 ? Wz : (g == 1 ? Wr : Wh)) +
                       (size_t)(rbase + row) * 1024 + 512 + 2 * cu;
    unsigned u = (unsigned)f2bf(src[0]) | ((unsigned)f2bf(src[1]) << 16);
    if (g < 2) sWZR[(g * ROWS + row) * WSTRIDE + cu] = u;
    else       sWH[row * WSTRIDE + cu] = u;
  }

  // phase A mapping: (gate z/r, row, 4 lanes x 128 cols)
  const int rgA = tid >> 2, gateA = rgA >> 5, rowA = rgA & 31, part4 = tid & 3;
  // phase B mapping: (row, 8 lanes x 64 cols)
  const int rowB = tid >> 3, part8 = tid & 7;

  unsigned long long* H8b = H8 + b * DH;
  unsigned long long* V8b = V8 + b * DH;
  const unsigned short* Gb = G + (size_t)b * S_ * NG3;

  __syncthreads();   // weights staged

  for (int t = 0; t < S_; ++t) {
    // prefetch this step's gate biases (overlaps the h poll)
    float gval = 0.f;
    if (tid < 96) {
      int gate = tid >> 5, i = tid & 31;
      gval = bf2f(Gb[(size_t)t * NG3 + gate * 512 + rbase + i]);
    }
    // ---- gather h^(t): poll tagged words (tag == t) ----
    {
      const unsigned tagH = (unsigned)t;
      unsigned long long* p0 = H8b + 2 * tid;
      float f0, f1;
      bool d0 = false, d1 = false;
      do {
        if (!d0) {
          unsigned long long w = __hip_atomic_load(p0, __ATOMIC_RELAXED, __HIP_MEMORY_SCOPE_AGENT);
          if ((unsigned)(w >> 32) == tagH) { f0 = __builtin_bit_cast(float, (unsigned)w); d0 = true; }
        }
        if (!d1) {
          unsigned long long w = __hip_atomic_load(p0 + 1, __ATOMIC_RELAXED, __HIP_MEMORY_SCOPE_AGENT);
          if ((unsigned)(w >> 32) == tagH) { f1 = __builtin_bit_cast(float, (unsigned)w); d1 = true; }
        }
      } while (!(d0 && d1));
      hbuf[2 * tid] = f0;
      hbuf[2 * tid + 1] = f1;
    }
    if (tid < 32) gz[tid] = gval;
    else if (tid < 64) gr[tid - 32] = gval;
    else if (tid < 96) gh[tid - 64] = gval;
    __syncthreads();

    // ---- phase A: z and r rows; publish v = r (.) h (tag t+1) ----
    {
      const float* hc = hbuf + part4 * 128;
      const unsigned* wp = sWZR + (gateA * ROWS + rowA) * WSTRIDE + part4 * 64;
      float s = 0.f;
#pragma unroll
      for (int j = 0; j < 64; j += 4) {
        uint4 w4 = *(const uint4*)(wp + j);
        float4 h0 = *(const float4*)(hc + 2 * j);
        float4 h1 = *(const float4*)(hc + 2 * j + 4);
        s += bflo(w4.x) * h0.x + bfhi(w4.x) * h0.y;
        s += bflo(w4.y) * h0.z + bfhi(w4.y) * h0.w;
        s += bflo(w4.z) * h1.x + bfhi(w4.z) * h1.y;
        s += bflo(w4.w) * h1.z + bfhi(w4.w) * h1.w;
      }
      s += __shfl_xor(s, 1);
      s += __shfl_xor(s, 2);
      float a = (gateA ? gr[rowA] : gz[rowA]) + s;
      float act = 1.f / (1.f + expf(-a));
      if (part4 == 0) {
        if (gateA == 0) {
          zb[rowA] = act;
        } else {
          float v = act * hbuf[rbase + rowA];
          __hip_atomic_store(V8b + rbase + rowA, tagword((unsigned)(t + 1), v),
                             __ATOMIC_RELAXED, __HIP_MEMORY_SCOPE_AGENT);
        }
      }
    }
    // ---- gather v (tag t+1) ----
    {
      const unsigned tagV = (unsigned)(t + 1);
      unsigned long long* p0 = V8b + 2 * tid;
      float f0, f1;
      bool d0 = false, d1 = false;
      do {
        if (!d0) {
          unsigned long long w = __hip_atomic_load(p0, __ATOMIC_RELAXED, __HIP_MEMORY_SCOPE_AGENT);
          if ((unsigned)(w >> 32) == tagV) { f0 = __builtin_bit_cast(float, (unsigned)w); d0 = true; }
        }
        if (!d1) {
          unsigned long long w = __hip_atomic_load(p0 + 1, __ATOMIC_RELAXED, __HIP_MEMORY_SCOPE_AGENT);
          if ((unsigned)(w >> 32) == tagV) { f1 = __builtin_bit_cast(float, (unsigned)w); d1 = true; }
        }
      } while (!(d0 && d1));
      vbuf[2 * tid] = f0;
      vbuf[2 * tid + 1] = f1;
    }
    __syncthreads();   // vbuf + zb ready

    // ---- phase B: h' rows, combine, publish h_new (tag t+1) ----
    {
      const float* vc = vbuf + part8 * 64;
      const unsigned* wp = sWH + rowB * WSTRIDE + part8 * 32;
      float s2 = 0.f;
#pragma unroll
      for (int j = 0; j < 32; j += 4) {
        uint4 w4 = *(const uint4*)(wp + j);
        float4 v0 = *(const float4*)(vc + 2 * j);
        float4 v1 = *(const float4*)(vc + 2 * j + 4);
        s2 += bflo(w4.x) * v0.x + bfhi(w4.x) * v0.y;
        s2 += bflo(w4.y) * v0.z + bfhi(w4.y) * v0.w;
        s2 += bflo(w4.z) * v1.x + bfhi(w4.z) * v1.y;
        s2 += bflo(w4.w) * v1.z + bfhi(w4.w) * v1.w;
      }
      s2 += __shfl_xor(s2, 1);
      s2 += __shfl_xor(s2, 2);
      s2 += __shfl_xor(s2, 4);
      float hp = tanhf(gh[rowB] + s2);
      float z = zb[rowB];
      float hold = hbuf[rbase + rowB];
      float hn = (1.f - z) * hold + z * hp;
      if (part8 == 0) {
        __hip_atomic_store(H8b + rbase + rowB, tagword((unsigned)(t + 1), hn),
                           __ATOMIC_RELAXED, __HIP_MEMORY_SCOPE_AGENT);
      }
    }
    __syncthreads();   // protects hbuf/vbuf/gz..zb before next iteration
  }
}

// ---------------------------------------------------------------------------
// classifier: out[8][10] = h_final @ W_c^T  (h from tagged words, low 32 bits)
// ---------------------------------------------------------------------------
__global__ void classifier_kernel(const unsigned long long* __restrict__ H8,
                                  const float* __restrict__ Wc,
                                  float* __restrict__ out) {
  int tid = threadIdx.x;
  if (tid < 80) {
    int b = tid / 10, c = tid % 10;
    const unsigned long long* h = H8 + b * DH;
    const float* w = Wc + (size_t)c * DH;
    float s = 0.f;
    for (int i = 0; i < DH; ++i) {
      float hv = __builtin_bit_cast(float, (unsigned)h[i]);
      s += hv * w[i];
    }
    out[tid] = s;
  }
}

extern "C" void kernel_launch(void* const* d_in, const int* in_sizes, int n_in,
                              void* d_out, int out_size, void* d_ws, size_t ws_size,
                              hipStream_t stream) {
  const float* X = (const float*)d_in[0];
  const float* Wlm = (const float*)d_in[1];
  const float* Wz = (const float*)d_in[2];
  const float* Wr = (const float*)d_in[3];
  const float* Wh = (const float*)d_in[4];
  const float* Wc = (const float*)d_in[5];
  float* out = (float*)d_out;

  char* ws = (char*)d_ws;
  unsigned short* seqb = (unsigned short*)ws;              // 33,554,432 B
  unsigned short* G = (unsigned short*)(ws + 33554432);    // 100,663,296 B
  unsigned short* Wp = (unsigned short*)(ws + 134217728);  // 1,572,864 B
  unsigned long long* H8 = (unsigned long long*)(ws + 135790592);  // 32 KB
  unsigned long long* V8 = (unsigned long long*)(ws + 135823360);  // 32 KB

  init_state<<<1, 256, 0, stream>>>(H8, V8);
  pack_w<<<768, 1024, 0, stream>>>(Wz, Wr, Wh, Wp);
  gemm1_kernel<<<dim3(512, 8), 256, 0, stream>>>(X, Wlm, seqb);
  gemm2_kernel<<<dim3(512, 24), 256, 0, stream>>>(seqb, Wp, G);

  {
    const int scan_lds = 104448;
    hipFuncSetAttribute((const void*)scan_kernel,
                        hipFuncAttributeMaxDynamicSharedMemorySize, scan_lds);
    const unsigned short* Gc = G;
    void* args[] = {(void*)&Gc, (void*)&Wz, (void*)&Wr, (void*)&Wh,
                    (void*)&H8, (void*)&V8};
    hipLaunchCooperativeKernel((const void*)scan_kernel, dim3(NG * B_), dim3(256),
                               args, scan_lds, stream);
  }
  classifier_kernel<<<1, 128, 0, stream>>>(H8, Wc, out);
}